// Round 5
// baseline (173.501 us; speedup 1.0000x reference)
//
#include <hip/hip_runtime.h>

typedef __attribute__((ext_vector_type(8))) short short8;
typedef __attribute__((ext_vector_type(4))) float f32x4;

#define NROWS 8192
#define DIM   1024
#define NCH   256
#define CHROW 32      // rows per chunk (NCH*CHROW == NROWS)

__device__ __forceinline__ float bf2f(unsigned short u) {
    union { unsigned int i; float f; } v; v.i = ((unsigned int)u) << 16; return v.f;
}
__device__ __forceinline__ unsigned short f2bf(float f) {
    union { float f; unsigned int i; } v; v.f = f;
    unsigned int r = v.i + 0x7fffu + ((v.i >> 16) & 1u);   // round-to-nearest-even
    return (unsigned short)(r >> 16);
}

// async global->LDS, 16 B per lane. LDS dest = wave-uniform base + lane*16.
__device__ __forceinline__ void gload_lds16(const unsigned short* g, unsigned short* l) {
    __builtin_amdgcn_global_load_lds(
        (const __attribute__((address_space(1))) void*)g,
        (__attribute__((address_space(3))) void*)l, 16, 0, 0);
}

// ---------------------------------------------------------------- K1: front
// blocks 0..511  : transpose-convert Wq/Wk -> WqT/WkT bf16, emit u/w partials
// blocks 512..767: cvt x fp32->bf16 + per-chunk column sums
__global__ __launch_bounds__(256) void front(
    const float* __restrict__ x,
    const float* __restrict__ Wq, const float* __restrict__ Wk,
    const float* __restrict__ bk, const float* __restrict__ bq,
    unsigned short* __restrict__ xb,
    unsigned short* __restrict__ WqT, unsigned short* __restrict__ WkT,
    float* __restrict__ pbuf,   // [32][1024] u/w partials (z*16+hblk)
    float* __restrict__ sums)
{
    __shared__ unsigned short tile[64][72];   // [a_local][h_local], padded
    __shared__ float su[64];
    const int t = threadIdx.x;
    const int b = blockIdx.x;

    if (b < 512) {
        const int z  = b >> 8;
        const int ax = b & 15, hy = (b >> 4) & 15;
        const float* W   = z ? Wk : Wq;
        const float* vec = z ? bq : bk;
        unsigned short* O = z ? WkT : WqT;
        const int h0 = hy * 64, a0 = ax * 64;
        if (t < 64) su[t] = 0.f;
        __syncthreads();

        const int inrow = t >> 4;          // 0..15 (h_local group)
        const int incol = (t & 15) * 4;    // 0..60 (a_local)
        float pu0 = 0.f, pu1 = 0.f, pu2 = 0.f, pu3 = 0.f;
        #pragma unroll
        for (int rr = 0; rr < 4; ++rr) {
            const int r = inrow + rr * 16;
            float4 v = *(const float4*)&W[(size_t)(h0 + r) * DIM + a0 + incol];
            float bv = vec[h0 + r];
            tile[incol + 0][r] = f2bf(v.x);
            tile[incol + 1][r] = f2bf(v.y);
            tile[incol + 2][r] = f2bf(v.z);
            tile[incol + 3][r] = f2bf(v.w);
            pu0 += v.x * bv; pu1 += v.y * bv; pu2 += v.z * bv; pu3 += v.w * bv;
        }
        atomicAdd(&su[incol + 0], pu0);
        atomicAdd(&su[incol + 1], pu1);
        atomicAdd(&su[incol + 2], pu2);
        atomicAdd(&su[incol + 3], pu3);
        __syncthreads();

        const int orow = t >> 2;           // 0..63 (a_local)
        const int ocol = (t & 3) * 16;     // 0,16,32,48 (h_local)
        short8 s0 = *(const short8*)&tile[orow][ocol];
        short8 s1 = *(const short8*)&tile[orow][ocol + 8];
        *(short8*)&O[(size_t)(a0 + orow) * DIM + h0 + ocol]     = s0;
        *(short8*)&O[(size_t)(a0 + orow) * DIM + h0 + ocol + 8] = s1;
        if (t < 64) pbuf[(size_t)(z * 16 + hy) * DIM + a0 + t] = su[t];
        return;
    }

    // ---- cvt x + chunk column sums (of the ROUNDED values)
    const int ch = b - 512;
    const int c4 = t * 4;
    float s0 = 0.f, s1 = 0.f, s2 = 0.f, s3 = 0.f;
    #pragma unroll 4
    for (int r = 0; r < CHROW; ++r) {
        size_t row = (size_t)ch * CHROW + r;
        float4 v = *(const float4*)&x[row * DIM + c4];
        ushort4 o;
        o.x = f2bf(v.x); o.y = f2bf(v.y); o.z = f2bf(v.z); o.w = f2bf(v.w);
        *(ushort4*)&xb[row * DIM + c4] = o;
        s0 += bf2f(o.x); s1 += bf2f(o.y); s2 += bf2f(o.z); s3 += bf2f(o.w);
    }
    f32x4 s; s[0] = s0; s[1] = s1; s[2] = s2; s[3] = s3;
    *(f32x4*)&sums[(size_t)ch * DIM + c4] = s;
}

// ---------------------------------------------------------------- K2: mid
// blocks 0..255 : gemm_g -> GT (double-buffered, swizzled LDS)
// blocks 256..259: exclusive chunk scan (offs)
// block  260    : c = bq . bk
// blocks 261..268: reduce pbuf -> u, w
__global__ __launch_bounds__(256) void mid(
    const unsigned short* __restrict__ WkT, const unsigned short* __restrict__ WqT,
    unsigned short* __restrict__ GTb,
    const float* __restrict__ sums, float* __restrict__ offs,
    const float* __restrict__ bq, const float* __restrict__ bk,
    float* __restrict__ cval,
    const float* __restrict__ pbuf, float* __restrict__ u, float* __restrict__ w)
{
    __shared__ unsigned short sT[2][2][64 * 64];   // [buf][A/B], 32 KB
    __shared__ float wsum[4];
    const int t = threadIdx.x;
    int b = blockIdx.x;

    if (b < 256) {
        const int K = DIM;
        const int wave = t >> 6, lane = t & 63;
        const int quad = lane >> 4, l16 = lane & 15;
        const int m0 = (b & 15) * 64, n0 = (b >> 4) * 64;
        const int wm = (wave >> 1) * 32, wn = (wave & 1) * 32;
        const int rsel = lane >> 3;
        const int csel = ((lane & 7) ^ (lane >> 3)) * 8;   // pre-swizzled source col
        const int sxor = l16 & 7;

        f32x4 acc[2][2];
        #pragma unroll
        for (int i = 0; i < 2; ++i)
            #pragma unroll
            for (int j = 0; j < 2; ++j) acc[i][j] = (f32x4)0.0f;

        #define STAGE_G(buf, kk) do {                                           \
            _Pragma("unroll")                                                   \
            for (int j = 0; j < 2; ++j) {                                       \
                const int row = wave * 16 + j * 8;                              \
                gload_lds16(WkT + (size_t)(m0 + row + rsel) * K + (kk) + csel,  \
                            &sT[buf][0][row * 64]);                             \
                gload_lds16(WqT + (size_t)(n0 + row + rsel) * K + (kk) + csel,  \
                            &sT[buf][1][row * 64]);                             \
            } } while (0)

        STAGE_G(0, 0);
        asm volatile("s_waitcnt vmcnt(0)" ::: "memory");
        __builtin_amdgcn_s_barrier();

        for (int tt = 0; tt < 16; ++tt) {
            const int cur = tt & 1;
            if (tt < 15) STAGE_G(cur ^ 1, (tt + 1) * 64);
            const unsigned short* cA = sT[cur][0];
            const unsigned short* cB = sT[cur][1];
            #pragma unroll
            for (int ks = 0; ks < 2; ++ks) {
                const int slot = (((ks * 4 + quad) ^ sxor) << 3);
                short8 af[2], bfr[2];
                af[0]  = *(const short8*)&cA[(wm + l16) * 64 + slot];
                af[1]  = *(const short8*)&cA[(wm + 16 + l16) * 64 + slot];
                bfr[0] = *(const short8*)&cB[(wn + l16) * 64 + slot];
                bfr[1] = *(const short8*)&cB[(wn + 16 + l16) * 64 + slot];
                #pragma unroll
                for (int mt = 0; mt < 2; ++mt)
                    #pragma unroll
                    for (int nt = 0; nt < 2; ++nt)
                        acc[mt][nt] = __builtin_amdgcn_mfma_f32_16x16x32_bf16(
                            af[mt], bfr[nt], acc[mt][nt], 0, 0, 0);
            }
            asm volatile("s_waitcnt vmcnt(0)" ::: "memory");
            __builtin_amdgcn_s_barrier();
        }
        #undef STAGE_G

        #pragma unroll
        for (int nt = 0; nt < 2; ++nt) {
            int n = n0 + wn + nt * 16 + l16;
            #pragma unroll
            for (int mt = 0; mt < 2; ++mt)
                #pragma unroll
                for (int r = 0; r < 4; ++r) {
                    int m = m0 + wm + mt * 16 + quad * 4 + r;
                    GTb[(size_t)m * DIM + n] = f2bf(acc[mt][nt][r]);
                }
        }
        return;
    }
    b -= 256;
    if (b < 4) {
        const int col = b * 256 + t;
        float run = 0.f;
        #pragma unroll 8
        for (int ch = 0; ch < NCH; ++ch) {
            float v = sums[(size_t)ch * DIM + col];
            offs[(size_t)ch * DIM + col] = run;
            run += v;
        }
        return;
    }
    if (b == 4) {
        float p = bq[t] * bk[t] + bq[t + 256] * bk[t + 256]
                + bq[t + 512] * bk[t + 512] + bq[t + 768] * bk[t + 768];
        #pragma unroll
        for (int s = 32; s >= 1; s >>= 1) p += __shfl_xor(p, s, 64);
        if ((t & 63) == 0) wsum[t >> 6] = p;
        __syncthreads();
        if (t == 0) cval[0] = wsum[0] + wsum[1] + wsum[2] + wsum[3];
        return;
    }
    b -= 5;
    const int idx = b * 256 + t;   // 0..2047
    if (idx < 1024) {
        float s = 0.f;
        #pragma unroll
        for (int h = 0; h < 16; ++h) s += pbuf[(size_t)h * DIM + idx];
        u[idx] = s;
    } else {
        const int a = idx - 1024;
        float s = 0.f;
        #pragma unroll
        for (int h = 0; h < 16; ++h) s += pbuf[(size_t)(16 + h) * DIM + a];
        w[a] = s;
    }
}

// ---------------------------------------------------------------- K3: gemm_z fused
// Z[i,b] = sum_a xb[i,a]*GT[b,a]; double-buffered LDS (T3 minimum 2-phase),
// XOR-swizzled tiles (T2 via pre-swizzled global source), s2 (u.x) folded in.
// Epilogue: single-pass fp32 P[128][128] (64 KB) + all-wave dot.
__global__ __launch_bounds__(256) void gemm_z_fused(
    const unsigned short* __restrict__ A,   // xb
    const unsigned short* __restrict__ B,   // GT
    const float* __restrict__ offs,
    const float* __restrict__ u, const float* __restrict__ w,
    float* __restrict__ s1part,   // [8192][16]  slot = by*2 + (wave&1)
    float* __restrict__ s2part)   // [8192][8]   slot = by
{
    const int K = DIM;
    __shared__ float smem[128 * 128];                // 64 KB
    unsigned short* sbuf[2][2];
    sbuf[0][0] = (unsigned short*)smem;              // buf0 A (16 KB)
    sbuf[0][1] = sbuf[0][0] + 128 * 64;              // buf0 B
    sbuf[1][0] = sbuf[0][1] + 128 * 64;              // buf1 A
    sbuf[1][1] = sbuf[1][0] + 128 * 64;              // buf1 B
    float* sP = smem;                                // epilogue P[128][128] swz

    const int tid = threadIdx.x;
    const int wave = tid >> 6, lane = tid & 63;
    const int quad = lane >> 4, l16 = lane & 15;
    const int m0 = blockIdx.x * 128, n0 = blockIdx.y * 128;
    const int by = blockIdx.y;
    const int wm = (wave >> 1) * 64, wn = (wave & 1) * 64;
    const int rsel = lane >> 3;
    const int csel = ((lane & 7) ^ (lane >> 3)) * 8;   // pre-swizzled source col
    const int sxor = l16 & 7;

    f32x4 acc[4][4];
    #pragma unroll
    for (int i = 0; i < 4; ++i)
        #pragma unroll
        for (int j = 0; j < 4; ++j) acc[i][j] = (f32x4)0.0f;

    float s2acc = 0.f;
    const int srow = tid >> 1;                // 0..127
    const int scol = (tid & 1) * 32;          // 0 / 32

    #define STAGE_Z(buf, kk) do {                                              \
        _Pragma("unroll")                                                      \
        for (int j = 0; j < 4; ++j) {                                          \
            const int row = wave * 32 + j * 8;                                 \
            gload_lds16(A + (size_t)(m0 + row + rsel) * K + (kk) + csel,       \
                        &sbuf[buf][0][row * 64]);                              \
            gload_lds16(B + (size_t)(n0 + row + rsel) * K + (kk) + csel,       \
                        &sbuf[buf][1][row * 64]);                              \
        } } while (0)

    STAGE_Z(0, 0);
    asm volatile("s_waitcnt vmcnt(0)" ::: "memory");
    __builtin_amdgcn_s_barrier();

    for (int tt = 0; tt < 16; ++tt) {
        const int cur = tt & 1;
        if (tt < 15) STAGE_Z(cur ^ 1, (tt + 1) * 64);
        const unsigned short* cA = sbuf[cur][0];
        const unsigned short* cB = sbuf[cur][1];
        #pragma unroll
        for (int ks = 0; ks < 2; ++ks) {
            const int slot = (((ks * 4 + quad) ^ sxor) << 3);
            short8 af[4], bfr[4];
            #pragma unroll
            for (int t2 = 0; t2 < 4; ++t2)
                af[t2] = *(const short8*)&cA[(wm + t2 * 16 + l16) * 64 + slot];
            #pragma unroll
            for (int t2 = 0; t2 < 4; ++t2)
                bfr[t2] = *(const short8*)&cB[(wn + t2 * 16 + l16) * 64 + slot];
            #pragma unroll
            for (int mt = 0; mt < 4; ++mt)
                #pragma unroll
                for (int nt = 0; nt < 4; ++nt)
                    acc[mt][nt] = __builtin_amdgcn_mfma_f32_16x16x32_bf16(
                        af[mt], bfr[nt], acc[mt][nt], 0, 0, 0);
        }
        if ((tt >> 1) == by) {
            // u . x partial over these 64 k-cols (cA re-read, swizzled addressing)
            const float* uu = u + tt * 64 + scol;
            float s = 0.f;
            #pragma unroll
            for (int c2 = 0; c2 < 32; ++c2) {
                const int c = scol + c2;
                s += bf2f(cA[srow * 64 + (c ^ ((srow & 7) << 3))]) * uu[c2];
            }
            s2acc += s;
        }
        asm volatile("s_waitcnt vmcnt(0)" ::: "memory");
        __builtin_amdgcn_s_barrier();
    }
    #undef STAGE_Z

    // write s2 partial (pairs share a row)
    {
        float v2 = s2acc + __shfl_xor(s2acc, 1, 64);
        if ((tid & 1) == 0) s2part[(size_t)(m0 + srow) * 8 + by] = v2;
    }

    // ---- epilogue: single pass, fp32 P[128][128] swizzled ------------------
    const int col   = tid & 127;           // 0..127 (local n)
    const int cpair = tid >> 7;            // 0..1
    const int ncol  = n0 + col;
    unsigned short xv0[32], xv1[32];
    float off0, off1;
    {
        const int chl0 = cpair * 2 + 0, chl1 = cpair * 2 + 1;
        const unsigned short* xc0 = A + (size_t)(m0 + chl0 * 32) * DIM + ncol;
        const unsigned short* xc1 = A + (size_t)(m0 + chl1 * 32) * DIM + ncol;
        #pragma unroll
        for (int r = 0; r < 32; ++r) xv0[r] = xc0[(size_t)r * DIM];
        #pragma unroll
        for (int r = 0; r < 32; ++r) xv1[r] = xc1[(size_t)r * DIM];
        off0 = offs[(size_t)((m0 >> 5) + chl0) * DIM + ncol];
        off1 = offs[(size_t)((m0 >> 5) + chl1) * DIM + ncol];
    }
    // main loop ended with a barrier: all LDS consumers done, safe to overwrite
    {
        const int rb0 = cpair * 64;
        float run = off0;
        #pragma unroll
        for (int r = 0; r < 32; ++r) {
            sP[(rb0 + r) * 128 + (col ^ (((r >> 2) & 3) << 4))] = run;
            run += bf2f(xv0[r]);
        }
        run = off1;
        #pragma unroll
        for (int r = 0; r < 32; ++r) {
            sP[(rb0 + 32 + r) * 128 + (col ^ (((r >> 2) & 3) << 4))] = run;
            run += bf2f(xv1[r]);
        }
    }
    __syncthreads();

    // Dot: all 4 waves. Wave covers rows wm..wm+63, cols wn..wn+63.
    {
        const int psw = quad << 4;
        float wv[4]; int cswz[4];
        #pragma unroll
        for (int nt = 0; nt < 4; ++nt) {
            wv[nt]   = w[n0 + wn + nt * 16 + l16];
            cswz[nt] = (wn + nt * 16 + l16) ^ psw;
        }
        #pragma unroll
        for (int mt = 0; mt < 4; ++mt) {
            #pragma unroll
            for (int r = 0; r < 4; ++r) {
                const int m_loc = wm + mt * 16 + quad * 4 + r;
                float val = 0.f;
                #pragma unroll
                for (int nt = 0; nt < 4; ++nt)
                    val += (acc[mt][nt][r] + wv[nt]) * sP[m_loc * 128 + cswz[nt]];
                val += __shfl_xor(val, 1, 64);
                val += __shfl_xor(val, 2, 64);
                val += __shfl_xor(val, 4, 64);
                val += __shfl_xor(val, 8, 64);
                if (l16 == 0)
                    s1part[(size_t)(m0 + m_loc) * 16 + by * 2 + (wave & 1)] = val;
            }
        }
    }
}

// ---------------------------------------------------------------- K4: bcast (per chunk)
// out[r][:] = sum16(s1part[r]) + r*(sum8(s2part[r]) + c)
__global__ __launch_bounds__(256) void bcast(
    const float* __restrict__ s1part, const float* __restrict__ s2part,
    const float* __restrict__ cval, float* __restrict__ out)
{
    __shared__ float rowval[CHROW];
    const int t = threadIdx.x, ch = blockIdx.x;
    if (t < CHROW) {
        const size_t row = (size_t)ch * CHROW + t;
        const float* p = &s1part[row * 16];
        float s = 0.f;
        #pragma unroll
        for (int j = 0; j < 16; ++j) s += p[j];
        const float* p2 = &s2part[row * 8];
        float s2 = 0.f;
        #pragma unroll
        for (int j = 0; j < 8; ++j) s2 += p2[j];
        rowval[t] = s + (float)row * (s2 + cval[0]);
    }
    __syncthreads();
    const int c4 = t * 4;
    #pragma unroll
    for (int r = 0; r < CHROW; ++r) {
        const size_t row = (size_t)ch * CHROW + r;
        f32x4 o = (f32x4)rowval[r];
        *(f32x4*)&out[row * DIM + c4] = o;
    }
}

// ---------------------------------------------------------------- launch
extern "C" void kernel_launch(void* const* d_in, const int* in_sizes, int n_in,
                              void* d_out, int out_size, void* d_ws, size_t ws_size,
                              hipStream_t stream)
{
    const float* x  = (const float*)d_in[0];
    const float* Wk = (const float*)d_in[1];
    const float* bk = (const float*)d_in[2];
    // d_in[3] = Wv, d_in[4] = bv : dead (reference overwrites V with ones)
    const float* Wq = (const float*)d_in[5];
    const float* bq = (const float*)d_in[6];
    float* out = (float*)d_out;

    char* ws = (char*)d_ws;
    unsigned short* xb  = (unsigned short*)(ws);                          // 16 MB
    unsigned short* GTb = (unsigned short*)(ws + (size_t)(16u << 20));    //  2 MB
    unsigned short* WqT = (unsigned short*)(ws + (size_t)(18u << 20));    //  2 MB
    unsigned short* WkT = (unsigned short*)(ws + (size_t)(20u << 20));    //  2 MB
    float* sums         = (float*)(ws + (size_t)(22u << 20));             //  1 MB
    float* offs         = (float*)(ws + (size_t)(23u << 20));             //  1 MB
    float* pbuf         = (float*)(ws + (size_t)(24u << 20));             // 128 KB
    float* u            = (float*)(ws + (size_t)(24u << 20) + (140u << 10)); // 4 KB
    float* w            = (float*)(ws + (size_t)(24u << 20) + (144u << 10)); // 4 KB
    float* cval         = (float*)(ws + (size_t)(24u << 20) + (148u << 10)); // 4 B
    float* s1part       = (float*)(ws + (size_t)(25u << 20));             // 512 KB
    float* s2part       = (float*)(ws + (size_t)(25u << 20) + (512u << 10)); // 256 KB

    front<<<768, 256, 0, stream>>>(x, Wq, Wk, bk, bq, xb, WqT, WkT, pbuf, sums);
    mid<<<269, 256, 0, stream>>>(WkT, WqT, GTb, sums, offs, bq, bk, cval, pbuf, u, w);
    gemm_z_fused<<<dim3(64, 8), 256, 0, stream>>>(xb, GTb, offs, u, w, s1part, s2part);
    bcast<<<256, 256, 0, stream>>>(s1part, s2part, cval, out);
}

// Round 6
// 163.451 us; speedup vs baseline: 1.0615x; 1.0615x over previous
//
#include <hip/hip_runtime.h>

typedef __attribute__((ext_vector_type(8))) short short8;
typedef __attribute__((ext_vector_type(4))) float f32x4;

#define NROWS 8192
#define DIM   1024
#define NCH   256
#define CHROW 32      // rows per chunk (NCH*CHROW == NROWS)

__device__ __forceinline__ float bf2f(unsigned short u) {
    union { unsigned int i; float f; } v; v.i = ((unsigned int)u) << 16; return v.f;
}
__device__ __forceinline__ unsigned short f2bf(float f) {
    union { float f; unsigned int i; } v; v.f = f;
    unsigned int r = v.i + 0x7fffu + ((v.i >> 16) & 1u);   // round-to-nearest-even
    return (unsigned short)(r >> 16);
}

// async global->LDS, 16 B per lane. LDS dest = wave-uniform base + lane*16.
__device__ __forceinline__ void gload_lds16(const unsigned short* g, unsigned short* l) {
    __builtin_amdgcn_global_load_lds(
        (const __attribute__((address_space(1))) void*)g,
        (__attribute__((address_space(3))) void*)l, 16, 0, 0);
}

// ---------------------------------------------------------------- K1: front
// blocks 0..511  : transpose-convert Wq/Wk -> WqT/WkT bf16, emit u/w partials
// blocks 512..767: cvt x fp32->bf16 + per-chunk column sums
__global__ __launch_bounds__(256) void front(
    const float* __restrict__ x,
    const float* __restrict__ Wq, const float* __restrict__ Wk,
    const float* __restrict__ bk, const float* __restrict__ bq,
    unsigned short* __restrict__ xb,
    unsigned short* __restrict__ WqT, unsigned short* __restrict__ WkT,
    float* __restrict__ pbuf,   // [32][1024] u/w partials (z*16+hblk)
    float* __restrict__ sums)
{
    __shared__ unsigned short tile[64][72];   // [a_local][h_local], padded
    __shared__ float su[64];
    const int t = threadIdx.x;
    const int b = blockIdx.x;

    if (b < 512) {
        const int z  = b >> 8;
        const int ax = b & 15, hy = (b >> 4) & 15;
        const float* W   = z ? Wk : Wq;
        const float* vec = z ? bq : bk;
        unsigned short* O = z ? WkT : WqT;
        const int h0 = hy * 64, a0 = ax * 64;
        if (t < 64) su[t] = 0.f;
        __syncthreads();

        const int inrow = t >> 4;          // 0..15 (h_local group)
        const int incol = (t & 15) * 4;    // 0..60 (a_local)
        float pu0 = 0.f, pu1 = 0.f, pu2 = 0.f, pu3 = 0.f;
        #pragma unroll
        for (int rr = 0; rr < 4; ++rr) {
            const int r = inrow + rr * 16;
            float4 v = *(const float4*)&W[(size_t)(h0 + r) * DIM + a0 + incol];
            float bv = vec[h0 + r];
            tile[incol + 0][r] = f2bf(v.x);
            tile[incol + 1][r] = f2bf(v.y);
            tile[incol + 2][r] = f2bf(v.z);
            tile[incol + 3][r] = f2bf(v.w);
            pu0 += v.x * bv; pu1 += v.y * bv; pu2 += v.z * bv; pu3 += v.w * bv;
        }
        atomicAdd(&su[incol + 0], pu0);
        atomicAdd(&su[incol + 1], pu1);
        atomicAdd(&su[incol + 2], pu2);
        atomicAdd(&su[incol + 3], pu3);
        __syncthreads();

        const int orow = t >> 2;           // 0..63 (a_local)
        const int ocol = (t & 3) * 16;     // 0,16,32,48 (h_local)
        short8 s0 = *(const short8*)&tile[orow][ocol];
        short8 s1 = *(const short8*)&tile[orow][ocol + 8];
        *(short8*)&O[(size_t)(a0 + orow) * DIM + h0 + ocol]     = s0;
        *(short8*)&O[(size_t)(a0 + orow) * DIM + h0 + ocol + 8] = s1;
        if (t < 64) pbuf[(size_t)(z * 16 + hy) * DIM + a0 + t] = su[t];
        return;
    }

    // ---- cvt x + chunk column sums (of the ROUNDED values)
    const int ch = b - 512;
    const int c4 = t * 4;
    float s0 = 0.f, s1 = 0.f, s2 = 0.f, s3 = 0.f;
    #pragma unroll 4
    for (int r = 0; r < CHROW; ++r) {
        size_t row = (size_t)ch * CHROW + r;
        float4 v = *(const float4*)&x[row * DIM + c4];
        ushort4 o;
        o.x = f2bf(v.x); o.y = f2bf(v.y); o.z = f2bf(v.z); o.w = f2bf(v.w);
        *(ushort4*)&xb[row * DIM + c4] = o;
        s0 += bf2f(o.x); s1 += bf2f(o.y); s2 += bf2f(o.z); s3 += bf2f(o.w);
    }
    f32x4 s; s[0] = s0; s[1] = s1; s[2] = s2; s[3] = s3;
    *(f32x4*)&sums[(size_t)ch * DIM + c4] = s;
}

// ---------------------------------------------------------------- K2: mid  (R4 verbatim)
// blocks 0..255 : gemm_g -> GT (GT[b][a] = G[a][b], G = Wq^T Wk)
// blocks 256..259: exclusive chunk scan (offs)
// block  260    : c = bq . bk
// blocks 261..268: reduce pbuf -> u, w
__global__ __launch_bounds__(256) void mid(
    const unsigned short* __restrict__ WkT, const unsigned short* __restrict__ WqT,
    unsigned short* __restrict__ GTb,
    const float* __restrict__ sums, float* __restrict__ offs,
    const float* __restrict__ bq, const float* __restrict__ bk,
    float* __restrict__ cval,
    const float* __restrict__ pbuf, float* __restrict__ u, float* __restrict__ w)
{
    __shared__ unsigned short sA[64 * 64];   // 8 KB
    __shared__ unsigned short sB[64 * 64];   // 8 KB
    __shared__ float wsum[4];
    const int t = threadIdx.x;
    int b = blockIdx.x;

    if (b < 256) {
        const int K = DIM;
        const int wave = t >> 6, lane = t & 63;
        const int quad = lane >> 4, l16 = lane & 15;
        const int m0 = (b & 15) * 64, n0 = (b >> 4) * 64;
        const int wm = (wave >> 1) * 32, wn = (wave & 1) * 32;
        const int rsel = lane >> 3, csel = (lane & 7) * 8;

        f32x4 acc[2][2];
        #pragma unroll
        for (int i = 0; i < 2; ++i)
            #pragma unroll
            for (int j = 0; j < 2; ++j) acc[i][j] = (f32x4)0.0f;

        for (int k0 = 0; k0 < K; k0 += 64) {
            __syncthreads();
            #pragma unroll
            for (int j = 0; j < 2; ++j) {
                const int row = wave * 16 + j * 8;
                gload_lds16(WkT + (size_t)(m0 + row + rsel) * K + k0 + csel, &sA[row * 64]);
                gload_lds16(WqT + (size_t)(n0 + row + rsel) * K + k0 + csel, &sB[row * 64]);
            }
            __syncthreads();
            #pragma unroll
            for (int ks = 0; ks < 2; ++ks) {
                const int kc = ks * 32 + quad * 8;
                short8 af[2], bfr[2];
                af[0]  = *(const short8*)&sA[(wm + l16) * 64 + kc];
                af[1]  = *(const short8*)&sA[(wm + 16 + l16) * 64 + kc];
                bfr[0] = *(const short8*)&sB[(wn + l16) * 64 + kc];
                bfr[1] = *(const short8*)&sB[(wn + 16 + l16) * 64 + kc];
                #pragma unroll
                for (int mt = 0; mt < 2; ++mt)
                    #pragma unroll
                    for (int nt = 0; nt < 2; ++nt)
                        acc[mt][nt] = __builtin_amdgcn_mfma_f32_16x16x32_bf16(
                            af[mt], bfr[nt], acc[mt][nt], 0, 0, 0);
            }
        }
        #pragma unroll
        for (int nt = 0; nt < 2; ++nt) {
            int n = n0 + wn + nt * 16 + l16;
            #pragma unroll
            for (int mt = 0; mt < 2; ++mt)
                #pragma unroll
                for (int r = 0; r < 4; ++r) {
                    int m = m0 + wm + mt * 16 + quad * 4 + r;
                    GTb[(size_t)m * DIM + n] = f2bf(acc[mt][nt][r]);
                }
        }
        return;
    }
    b -= 256;
    if (b < 4) {
        const int col = b * 256 + t;
        float run = 0.f;
        #pragma unroll 8
        for (int ch = 0; ch < NCH; ++ch) {
            float v = sums[(size_t)ch * DIM + col];
            offs[(size_t)ch * DIM + col] = run;
            run += v;
        }
        return;
    }
    if (b == 4) {
        float p = bq[t] * bk[t] + bq[t + 256] * bk[t + 256]
                + bq[t + 512] * bk[t + 512] + bq[t + 768] * bk[t + 768];
        #pragma unroll
        for (int s = 32; s >= 1; s >>= 1) p += __shfl_xor(p, s, 64);
        if ((t & 63) == 0) wsum[t >> 6] = p;
        __syncthreads();
        if (t == 0) cval[0] = wsum[0] + wsum[1] + wsum[2] + wsum[3];
        return;
    }
    b -= 5;
    const int idx = b * 256 + t;   // 0..2047
    if (idx < 1024) {
        float s = 0.f;
        #pragma unroll
        for (int h = 0; h < 16; ++h) s += pbuf[(size_t)h * DIM + idx];
        u[idx] = s;
    } else {
        const int a = idx - 1024;
        float s = 0.f;
        #pragma unroll
        for (int h = 0; h < 16; ++h) s += pbuf[(size_t)(16 + h) * DIM + a];
        w[a] = s;
    }
}

// ---------------------------------------------------------------- K3: gemm_z fused
// Z[i,b] = sum_a xb[i,a]*GT[b,a]; STATIC double-buffer 2-phase (stage next tile
// before compute, one __syncthreads per K-step; all buffer refs compile-time).
// XOR-swizzled tiles (T2 via pre-swizzled global source), s2 (u.x) folded in.
// Epilogue: R4's two 64-row half passes (32 KB P, swizzled).
__global__ __launch_bounds__(256) void gemm_z_fused(
    const unsigned short* __restrict__ A,   // xb
    const unsigned short* __restrict__ B,   // GT
    const float* __restrict__ offs,
    const float* __restrict__ u, const float* __restrict__ w,
    float* __restrict__ s1part,   // [8192][16]  slot = by*2 + (wave&1)
    float* __restrict__ s2part)   // [8192][8]   slot = by
{
    const int K = DIM;
    __shared__ float smem[128 * 128];                    // 64 KB
    unsigned short* const sA0 = (unsigned short*)smem;   // 16 KB
    unsigned short* const sB0 = sA0 + 128 * 64;          // 16 KB
    unsigned short* const sA1 = sB0 + 128 * 64;          // 16 KB
    unsigned short* const sB1 = sA1 + 128 * 64;          // 16 KB
    float* const sP = smem;                              // epilogue P half-tile [64][128]

    const int tid = threadIdx.x;
    const int wave = tid >> 6, lane = tid & 63;
    const int quad = lane >> 4, l16 = lane & 15;
    const int m0 = blockIdx.x * 128, n0 = blockIdx.y * 128;
    const int by = blockIdx.y;
    const int wm = (wave >> 1) * 64, wn = (wave & 1) * 64;
    const int rsel = lane >> 3;
    const int csel = ((lane & 7) ^ (lane >> 3)) * 8;   // pre-swizzled source col
    const int sxor = l16 & 7;

    f32x4 acc[4][4];
    #pragma unroll
    for (int i = 0; i < 4; ++i)
        #pragma unroll
        for (int j = 0; j < 4; ++j) acc[i][j] = (f32x4)0.0f;

    float s2acc = 0.f;
    const int srow = tid >> 1;                // 0..127
    const int scol = (tid & 1) * 32;          // 0 / 32

    #define STAGE_Z(pa, pb, kk) do {                                           \
        _Pragma("unroll")                                                      \
        for (int j = 0; j < 4; ++j) {                                          \
            const int row = wave * 32 + j * 8;                                 \
            gload_lds16(A + (size_t)(m0 + row + rsel) * K + (kk) + csel,       \
                        &(pa)[row * 64]);                                      \
            gload_lds16(B + (size_t)(n0 + row + rsel) * K + (kk) + csel,       \
                        &(pb)[row * 64]);                                      \
        } } while (0)

    #define COMPUTE_Z(pa, pb, tt) do {                                         \
        _Pragma("unroll")                                                      \
        for (int ks = 0; ks < 2; ++ks) {                                       \
            const int slot = (((ks * 4 + quad) ^ sxor) << 3);                  \
            short8 af[4], bfr[4];                                              \
            _Pragma("unroll")                                                  \
            for (int t2 = 0; t2 < 4; ++t2)                                     \
                af[t2] = *(const short8*)&(pa)[(wm + t2 * 16 + l16) * 64 + slot]; \
            _Pragma("unroll")                                                  \
            for (int t2 = 0; t2 < 4; ++t2)                                     \
                bfr[t2] = *(const short8*)&(pb)[(wn + t2 * 16 + l16) * 64 + slot]; \
            _Pragma("unroll")                                                  \
            for (int mt = 0; mt < 4; ++mt)                                     \
                _Pragma("unroll")                                              \
                for (int nt = 0; nt < 4; ++nt)                                 \
                    acc[mt][nt] = __builtin_amdgcn_mfma_f32_16x16x32_bf16(     \
                        af[mt], bfr[nt], acc[mt][nt], 0, 0, 0);                \
        }                                                                      \
        if (((tt) >> 1) == by) {                                               \
            const float* uu = u + (tt) * 64 + scol;                            \
            float s = 0.f;                                                     \
            _Pragma("unroll")                                                  \
            for (int c2 = 0; c2 < 32; ++c2) {                                  \
                const int c = scol + c2;                                       \
                s += bf2f((pa)[srow * 64 + (c ^ ((srow & 7) << 3))]) * uu[c2]; \
            }                                                                  \
            s2acc += s;                                                        \
        } } while (0)

    STAGE_Z(sA0, sB0, 0);
    __syncthreads();
    for (int tt = 0; tt < 16; tt += 2) {
        // phase A: stage tile tt+1 into buf1, compute tile tt from buf0
        STAGE_Z(sA1, sB1, (tt + 1) * 64);          // tt+1 <= 15 always
        COMPUTE_Z(sA0, sB0, tt);
        __syncthreads();                           // drains vmcnt, buf1 ready
        // phase B: stage tile tt+2 into buf0, compute tile tt+1 from buf1
        if (tt < 14) STAGE_Z(sA0, sB0, (tt + 2) * 64);
        COMPUTE_Z(sA1, sB1, tt + 1);
        __syncthreads();                           // buf0 ready for next iter
    }
    #undef STAGE_Z
    #undef COMPUTE_Z

    // write s2 partial (pairs share a row)
    {
        float v2 = s2acc + __shfl_xor(s2acc, 1, 64);
        if ((tid & 1) == 0) s2part[(size_t)(m0 + srow) * 8 + by] = v2;
    }

    // ---- epilogue: two 64-row half passes, P fp32 [64][128] swizzled (R4) --
    const int pcol = tid & 127;        // column owner
    const int psub = tid >> 7;         // which 32-row chunk of the half
    const int ncol = n0 + pcol;
    unsigned short xv[32];
    float offv;
    // half 0 loads (rows m0 .. m0+63)
    {
        const unsigned short* xc = A + (size_t)(m0 + psub * 32) * DIM + ncol;
        #pragma unroll
        for (int r = 0; r < 32; ++r) xv[r] = xc[(size_t)r * DIM];
        offv = offs[(size_t)((m0 >> 5) + psub) * DIM + ncol];
    }
    __syncthreads();                   // main-loop LDS consumers done
    {
        float run = offv;
        #pragma unroll
        for (int r = 0; r < 32; ++r) {
            const int row = psub * 32 + r;
            sP[row * 128 + (pcol ^ (((row >> 2) & 3) << 4))] = run;
            run += bf2f(xv[r]);
        }
    }
    __syncthreads();                   // P half-0 ready
    // issue half-1 loads now (overlap with dot pass 0)
    {
        const unsigned short* xc = A + (size_t)(m0 + 64 + psub * 32) * DIM + ncol;
        #pragma unroll
        for (int r = 0; r < 32; ++r) xv[r] = xc[(size_t)r * DIM];
        offv = offs[(size_t)((m0 >> 5) + 2 + psub) * DIM + ncol];
    }
    if (wave < 2) {                    // rows m0..m0+63 owners (wm == 0)
        const int psw = quad << 4;
        float wv[4]; int cswz[4];
        #pragma unroll
        for (int nt = 0; nt < 4; ++nt) {
            wv[nt]   = w[n0 + wn + nt * 16 + l16];
            cswz[nt] = (wn + nt * 16 + l16) ^ psw;
        }
        #pragma unroll
        for (int mt = 0; mt < 4; ++mt) {
            #pragma unroll
            for (int r = 0; r < 4; ++r) {
                const int lr = mt * 16 + quad * 4 + r;
                float val = 0.f;
                #pragma unroll
                for (int nt = 0; nt < 4; ++nt)
                    val += (acc[mt][nt][r] + wv[nt]) * sP[lr * 128 + cswz[nt]];
                val += __shfl_xor(val, 1, 64);
                val += __shfl_xor(val, 2, 64);
                val += __shfl_xor(val, 4, 64);
                val += __shfl_xor(val, 8, 64);
                if (l16 == 0)
                    s1part[(size_t)(m0 + lr) * 16 + by * 2 + (wave & 1)] = val;
            }
        }
    }
    __syncthreads();                   // dot0 done; xv half-1 arrived
    {
        float run = offv;
        #pragma unroll
        for (int r = 0; r < 32; ++r) {
            const int row = psub * 32 + r;
            sP[row * 128 + (pcol ^ (((row >> 2) & 3) << 4))] = run;
            run += bf2f(xv[r]);
        }
    }
    __syncthreads();                   // P half-1 ready
    if (wave >= 2) {                   // rows m0+64..m0+127 owners (wm == 64)
        const int psw = quad << 4;
        float wv[4]; int cswz[4];
        #pragma unroll
        for (int nt = 0; nt < 4; ++nt) {
            wv[nt]   = w[n0 + wn + nt * 16 + l16];
            cswz[nt] = (wn + nt * 16 + l16) ^ psw;
        }
        #pragma unroll
        for (int mt = 0; mt < 4; ++mt) {
            #pragma unroll
            for (int r = 0; r < 4; ++r) {
                const int lr = mt * 16 + quad * 4 + r;
                float val = 0.f;
                #pragma unroll
                for (int nt = 0; nt < 4; ++nt)
                    val += (acc[mt][nt][r] + wv[nt]) * sP[lr * 128 + cswz[nt]];
                val += __shfl_xor(val, 1, 64);
                val += __shfl_xor(val, 2, 64);
                val += __shfl_xor(val, 4, 64);
                val += __shfl_xor(val, 8, 64);
                if (l16 == 0)
                    s1part[(size_t)(m0 + 64 + lr) * 16 + by * 2 + (wave & 1)] = val;
            }
        }
    }
}

// ---------------------------------------------------------------- K4: bcast (per chunk)
// out[r][:] = sum16(s1part[r]) + r*(sum8(s2part[r]) + c)
__global__ __launch_bounds__(256) void bcast(
    const float* __restrict__ s1part, const float* __restrict__ s2part,
    const float* __restrict__ cval, float* __restrict__ out)
{
    __shared__ float rowval[CHROW];
    const int t = threadIdx.x, ch = blockIdx.x;
    if (t < CHROW) {
        const size_t row = (size_t)ch * CHROW + t;
        const float* p = &s1part[row * 16];
        float s = 0.f;
        #pragma unroll
        for (int j = 0; j < 16; ++j) s += p[j];
        const float* p2 = &s2part[row * 8];
        float s2 = 0.f;
        #pragma unroll
        for (int j = 0; j < 8; ++j) s2 += p2[j];
        rowval[t] = s + (float)row * (s2 + cval[0]);
    }
    __syncthreads();
    const int c4 = t * 4;
    #pragma unroll
    for (int r = 0; r < CHROW; ++r) {
        const size_t row = (size_t)ch * CHROW + r;
        f32x4 o = (f32x4)rowval[r];
        *(f32x4*)&out[row * DIM + c4] = o;
    }
}

// ---------------------------------------------------------------- launch
extern "C" void kernel_launch(void* const* d_in, const int* in_sizes, int n_in,
                              void* d_out, int out_size, void* d_ws, size_t ws_size,
                              hipStream_t stream)
{
    const float* x  = (const float*)d_in[0];
    const float* Wk = (const float*)d_in[1];
    const float* bk = (const float*)d_in[2];
    // d_in[3] = Wv, d_in[4] = bv : dead (reference overwrites V with ones)
    const float* Wq = (const float*)d_in[5];
    const float* bq = (const float*)d_in[6];
    float* out = (float*)d_out;

    char* ws = (char*)d_ws;
    unsigned short* xb  = (unsigned short*)(ws);                          // 16 MB
    unsigned short* GTb = (unsigned short*)(ws + (size_t)(16u << 20));    //  2 MB
    unsigned short* WqT = (unsigned short*)(ws + (size_t)(18u << 20));    //  2 MB
    unsigned short* WkT = (unsigned short*)(ws + (size_t)(20u << 20));    //  2 MB
    float* sums         = (float*)(ws + (size_t)(22u << 20));             //  1 MB
    float* offs         = (float*)(ws + (size_t)(23u << 20));             //  1 MB
    float* pbuf         = (float*)(ws + (size_t)(24u << 20));             // 128 KB
    float* u            = (float*)(ws + (size_t)(24u << 20) + (140u << 10)); // 4 KB
    float* w            = (float*)(ws + (size_t)(24u << 20) + (144u << 10)); // 4 KB
    float* cval         = (float*)(ws + (size_t)(24u << 20) + (148u << 10)); // 4 B
    float* s1part       = (float*)(ws + (size_t)(25u << 20));             // 512 KB
    float* s2part       = (float*)(ws + (size_t)(25u << 20) + (512u << 10)); // 256 KB

    front<<<768, 256, 0, stream>>>(x, Wq, Wk, bk, bq, xb, WqT, WkT, pbuf, sums);
    mid<<<269, 256, 0, stream>>>(WkT, WqT, GTb, sums, offs, bq, bk, cval, pbuf, u, w);
    gemm_z_fused<<<dim3(64, 8), 256, 0, stream>>>(xb, GTb, offs, u, w, s1part, s2part);
    bcast<<<256, 256, 0, stream>>>(s1part, s2part, cval, out);
}

// Round 7
// 151.960 us; speedup vs baseline: 1.1417x; 1.0756x over previous
//
#include <hip/hip_runtime.h>

typedef __attribute__((ext_vector_type(8))) short short8;
typedef __attribute__((ext_vector_type(4))) float f32x4;

#define NROWS 8192
#define DIM   1024
#define NCH   256
#define CHROW 32      // rows per chunk (NCH*CHROW == NROWS)

__device__ __forceinline__ float bf2f(unsigned short u) {
    union { unsigned int i; float f; } v; v.i = ((unsigned int)u) << 16; return v.f;
}
__device__ __forceinline__ unsigned short f2bf(float f) {
    union { float f; unsigned int i; } v; v.f = f;
    unsigned int r = v.i + 0x7fffu + ((v.i >> 16) & 1u);   // round-to-nearest-even
    return (unsigned short)(r >> 16);
}

// async global->LDS, 16 B per lane. LDS dest = wave-uniform base + lane*16.
__device__ __forceinline__ void gload_lds16(const unsigned short* g, unsigned short* l) {
    __builtin_amdgcn_global_load_lds(
        (const __attribute__((address_space(1))) void*)g,
        (__attribute__((address_space(3))) void*)l, 16, 0, 0);
}

// ---------------------------------------------------------------- K1: front
// blocks 0..511  : transpose-convert Wq/Wk -> WqT/WkT bf16, emit u/w partials
// blocks 512..767: cvt x fp32->bf16 + per-chunk column sums
__global__ __launch_bounds__(256) void front(
    const float* __restrict__ x,
    const float* __restrict__ Wq, const float* __restrict__ Wk,
    const float* __restrict__ bk, const float* __restrict__ bq,
    unsigned short* __restrict__ xb,
    unsigned short* __restrict__ WqT, unsigned short* __restrict__ WkT,
    float* __restrict__ pbuf,   // [32][1024] u/w partials (z*16+hblk)
    float* __restrict__ sums)
{
    __shared__ unsigned short tile[64][72];   // [a_local][h_local], padded
    __shared__ float su[64];
    const int t = threadIdx.x;
    const int b = blockIdx.x;

    if (b < 512) {
        const int z  = b >> 8;
        const int ax = b & 15, hy = (b >> 4) & 15;
        const float* W   = z ? Wk : Wq;
        const float* vec = z ? bq : bk;
        unsigned short* O = z ? WkT : WqT;
        const int h0 = hy * 64, a0 = ax * 64;
        if (t < 64) su[t] = 0.f;
        __syncthreads();

        const int inrow = t >> 4;          // 0..15 (h_local group)
        const int incol = (t & 15) * 4;    // 0..60 (a_local)
        float pu0 = 0.f, pu1 = 0.f, pu2 = 0.f, pu3 = 0.f;
        #pragma unroll
        for (int rr = 0; rr < 4; ++rr) {
            const int r = inrow + rr * 16;
            float4 v = *(const float4*)&W[(size_t)(h0 + r) * DIM + a0 + incol];
            float bv = vec[h0 + r];
            tile[incol + 0][r] = f2bf(v.x);
            tile[incol + 1][r] = f2bf(v.y);
            tile[incol + 2][r] = f2bf(v.z);
            tile[incol + 3][r] = f2bf(v.w);
            pu0 += v.x * bv; pu1 += v.y * bv; pu2 += v.z * bv; pu3 += v.w * bv;
        }
        atomicAdd(&su[incol + 0], pu0);
        atomicAdd(&su[incol + 1], pu1);
        atomicAdd(&su[incol + 2], pu2);
        atomicAdd(&su[incol + 3], pu3);
        __syncthreads();

        const int orow = t >> 2;           // 0..63 (a_local)
        const int ocol = (t & 3) * 16;     // 0,16,32,48 (h_local)
        short8 s0 = *(const short8*)&tile[orow][ocol];
        short8 s1 = *(const short8*)&tile[orow][ocol + 8];
        *(short8*)&O[(size_t)(a0 + orow) * DIM + h0 + ocol]     = s0;
        *(short8*)&O[(size_t)(a0 + orow) * DIM + h0 + ocol + 8] = s1;
        if (t < 64) pbuf[(size_t)(z * 16 + hy) * DIM + a0 + t] = su[t];
        return;
    }

    // ---- cvt x + chunk column sums (of the ROUNDED values)
    const int ch = b - 512;
    const int c4 = t * 4;
    float s0 = 0.f, s1 = 0.f, s2 = 0.f, s3 = 0.f;
    #pragma unroll 4
    for (int r = 0; r < CHROW; ++r) {
        size_t row = (size_t)ch * CHROW + r;
        float4 v = *(const float4*)&x[row * DIM + c4];
        ushort4 o;
        o.x = f2bf(v.x); o.y = f2bf(v.y); o.z = f2bf(v.z); o.w = f2bf(v.w);
        *(ushort4*)&xb[row * DIM + c4] = o;
        s0 += bf2f(o.x); s1 += bf2f(o.y); s2 += bf2f(o.z); s3 += bf2f(o.w);
    }
    f32x4 s; s[0] = s0; s[1] = s1; s[2] = s2; s[3] = s3;
    *(f32x4*)&sums[(size_t)ch * DIM + c4] = s;
}

// ---------------------------------------------------------------- K2: mid
// blocks 0..255 : gemm_g -> GT (serial loop, T2-swizzled LDS)
// blocks 256..259: exclusive chunk scan (offs)
// block  260    : c = bq . bk
// blocks 261..268: reduce pbuf -> u, w
__global__ __launch_bounds__(256) void mid(
    const unsigned short* __restrict__ WkT, const unsigned short* __restrict__ WqT,
    unsigned short* __restrict__ GTb,
    const float* __restrict__ sums, float* __restrict__ offs,
    const float* __restrict__ bq, const float* __restrict__ bk,
    float* __restrict__ cval,
    const float* __restrict__ pbuf, float* __restrict__ u, float* __restrict__ w)
{
    __shared__ unsigned short sA[64 * 64];   // 8 KB
    __shared__ unsigned short sB[64 * 64];   // 8 KB
    __shared__ float wsum[4];
    const int t = threadIdx.x;
    int b = blockIdx.x;

    if (b < 256) {
        const int K = DIM;
        const int wave = t >> 6, lane = t & 63;
        const int quad = lane >> 4, l16 = lane & 15;
        const int m0 = (b & 15) * 64, n0 = (b >> 4) * 64;
        const int wm = (wave >> 1) * 32, wn = (wave & 1) * 32;
        const int rsel = lane >> 3;
        const int csel = ((lane & 7) ^ (lane >> 3)) * 8;   // pre-swizzled source col
        const int sxor = l16 & 7;

        f32x4 acc[2][2];
        #pragma unroll
        for (int i = 0; i < 2; ++i)
            #pragma unroll
            for (int j = 0; j < 2; ++j) acc[i][j] = (f32x4)0.0f;

        for (int k0 = 0; k0 < K; k0 += 64) {
            __syncthreads();
            #pragma unroll
            for (int j = 0; j < 2; ++j) {
                const int row = wave * 16 + j * 8;
                gload_lds16(WkT + (size_t)(m0 + row + rsel) * K + k0 + csel, &sA[row * 64]);
                gload_lds16(WqT + (size_t)(n0 + row + rsel) * K + k0 + csel, &sB[row * 64]);
            }
            __syncthreads();
            #pragma unroll
            for (int ks = 0; ks < 2; ++ks) {
                const int slot = (((ks * 4 + quad) ^ sxor) << 3);
                short8 af[2], bfr[2];
                af[0]  = *(const short8*)&sA[(wm + l16) * 64 + slot];
                af[1]  = *(const short8*)&sA[(wm + 16 + l16) * 64 + slot];
                bfr[0] = *(const short8*)&sB[(wn + l16) * 64 + slot];
                bfr[1] = *(const short8*)&sB[(wn + 16 + l16) * 64 + slot];
                #pragma unroll
                for (int mt = 0; mt < 2; ++mt)
                    #pragma unroll
                    for (int nt = 0; nt < 2; ++nt)
                        acc[mt][nt] = __builtin_amdgcn_mfma_f32_16x16x32_bf16(
                            af[mt], bfr[nt], acc[mt][nt], 0, 0, 0);
            }
        }
        #pragma unroll
        for (int nt = 0; nt < 2; ++nt) {
            int n = n0 + wn + nt * 16 + l16;
            #pragma unroll
            for (int mt = 0; mt < 2; ++mt)
                #pragma unroll
                for (int r = 0; r < 4; ++r) {
                    int m = m0 + wm + mt * 16 + quad * 4 + r;
                    GTb[(size_t)m * DIM + n] = f2bf(acc[mt][nt][r]);
                }
        }
        return;
    }
    b -= 256;
    if (b < 4) {
        const int col = b * 256 + t;
        float run = 0.f;
        #pragma unroll 8
        for (int ch = 0; ch < NCH; ++ch) {
            float v = sums[(size_t)ch * DIM + col];
            offs[(size_t)ch * DIM + col] = run;
            run += v;
        }
        return;
    }
    if (b == 4) {
        float p = bq[t] * bk[t] + bq[t + 256] * bk[t + 256]
                + bq[t + 512] * bk[t + 512] + bq[t + 768] * bk[t + 768];
        #pragma unroll
        for (int s = 32; s >= 1; s >>= 1) p += __shfl_xor(p, s, 64);
        if ((t & 63) == 0) wsum[t >> 6] = p;
        __syncthreads();
        if (t == 0) cval[0] = wsum[0] + wsum[1] + wsum[2] + wsum[3];
        return;
    }
    b -= 5;
    const int idx = b * 256 + t;   // 0..2047
    if (idx < 1024) {
        float s = 0.f;
        #pragma unroll
        for (int h = 0; h < 16; ++h) s += pbuf[(size_t)h * DIM + idx];
        u[idx] = s;
    } else {
        const int a = idx - 1024;
        float s = 0.f;
        #pragma unroll
        for (int h = 0; h < 16; ++h) s += pbuf[(size_t)(16 + h) * DIM + a];
        w[a] = s;
    }
}

// ---------------------------------------------------------------- K3: gemm_z fused
// Z[i,b] = sum_a xb[i,a]*GT[b,a]; SERIAL 2-barrier main loop (R4 structure —
// dbuf attempts R5/R6 both regressed; implicit 2-block/CU overlap suffices).
// XOR-swizzled tiles (T2 via pre-swizzled global source), s2 (u.x) folded in.
// Epilogue: single-pass fp32 P[128][128] (64 KB, swizzled) + all-wave dot.
__global__ __launch_bounds__(256) void gemm_z_fused(
    const unsigned short* __restrict__ A,   // xb
    const unsigned short* __restrict__ B,   // GT
    const float* __restrict__ offs,
    const float* __restrict__ u, const float* __restrict__ w,
    float* __restrict__ s1part,   // [8192][16]  slot = by*2 + (wave&1)
    float* __restrict__ s2part)   // [8192][8]   slot = by
{
    const int K = DIM;
    __shared__ float smem[128 * 128];                    // 64 KB
    unsigned short* const sA = (unsigned short*)smem;    // 16 KB staging A
    unsigned short* const sB = sA + 128 * 64;            // 16 KB staging B
    float* const sP = smem;                              // epilogue P[128][128] swz

    const int tid = threadIdx.x;
    const int wave = tid >> 6, lane = tid & 63;
    const int quad = lane >> 4, l16 = lane & 15;
    const int m0 = blockIdx.x * 128, n0 = blockIdx.y * 128;
    const int by = blockIdx.y;
    const int wm = (wave >> 1) * 64, wn = (wave & 1) * 64;
    const int rsel = lane >> 3;
    const int csel = ((lane & 7) ^ (lane >> 3)) * 8;   // pre-swizzled source col
    const int sxor = l16 & 7;

    f32x4 acc[4][4];
    #pragma unroll
    for (int i = 0; i < 4; ++i)
        #pragma unroll
        for (int j = 0; j < 4; ++j) acc[i][j] = (f32x4)0.0f;

    float s2acc = 0.f;
    const int srow = tid >> 1;                // 0..127
    const int scol = (tid & 1) * 32;          // 0 / 32

    for (int k0 = 0; k0 < K; k0 += 64) {
        __syncthreads();
        #pragma unroll
        for (int j = 0; j < 4; ++j) {
            const int row = wave * 32 + j * 8;
            gload_lds16(A + (size_t)(m0 + row + rsel) * K + k0 + csel, &sA[row * 64]);
            gload_lds16(B + (size_t)(n0 + row + rsel) * K + k0 + csel, &sB[row * 64]);
        }
        __syncthreads();
        #pragma unroll
        for (int ks = 0; ks < 2; ++ks) {
            const int slot = (((ks * 4 + quad) ^ sxor) << 3);
            short8 af[4], bfr[4];
            #pragma unroll
            for (int t2 = 0; t2 < 4; ++t2)
                af[t2] = *(const short8*)&sA[(wm + t2 * 16 + l16) * 64 + slot];
            #pragma unroll
            for (int t2 = 0; t2 < 4; ++t2)
                bfr[t2] = *(const short8*)&sB[(wn + t2 * 16 + l16) * 64 + slot];
            #pragma unroll
            for (int mt = 0; mt < 4; ++mt)
                #pragma unroll
                for (int nt = 0; nt < 4; ++nt)
                    acc[mt][nt] = __builtin_amdgcn_mfma_f32_16x16x32_bf16(
                        af[mt], bfr[nt], acc[mt][nt], 0, 0, 0);
        }
        if ((k0 >> 7) == by) {
            // u . x partial over these 64 k-cols (sA re-read, swizzled addressing)
            const float* uu = u + k0 + scol;
            float s = 0.f;
            #pragma unroll
            for (int c2 = 0; c2 < 32; ++c2) {
                const int c = scol + c2;
                s += bf2f(sA[srow * 64 + (c ^ ((srow & 7) << 3))]) * uu[c2];
            }
            s2acc += s;
        }
    }

    // write s2 partial (pairs share a row)
    {
        float v2 = s2acc + __shfl_xor(s2acc, 1, 64);
        if ((tid & 1) == 0) s2part[(size_t)(m0 + srow) * 8 + by] = v2;
    }

    // ---- epilogue: single pass, fp32 P[128][128] swizzled ------------------
    const int col   = tid & 127;           // 0..127 (local n)
    const int cpair = tid >> 7;            // 0..1
    const int ncol  = n0 + col;
    unsigned short xv0[32], xv1[32];
    float off0, off1;
    {
        const int chl0 = cpair * 2 + 0, chl1 = cpair * 2 + 1;
        const unsigned short* xc0 = A + (size_t)(m0 + chl0 * 32) * DIM + ncol;
        const unsigned short* xc1 = A + (size_t)(m0 + chl1 * 32) * DIM + ncol;
        #pragma unroll
        for (int r = 0; r < 32; ++r) xv0[r] = xc0[(size_t)r * DIM];
        #pragma unroll
        for (int r = 0; r < 32; ++r) xv1[r] = xc1[(size_t)r * DIM];
        off0 = offs[(size_t)((m0 >> 5) + chl0) * DIM + ncol];
        off1 = offs[(size_t)((m0 >> 5) + chl1) * DIM + ncol];
    }
    __syncthreads();   // all LDS reads of the last GEMM tile complete
    {
        const int rb0 = cpair * 64;
        float run = off0;
        #pragma unroll
        for (int r = 0; r < 32; ++r) {
            sP[(rb0 + r) * 128 + (col ^ (((r >> 2) & 3) << 4))] = run;
            run += bf2f(xv0[r]);
        }
        run = off1;
        #pragma unroll
        for (int r = 0; r < 32; ++r) {
            sP[(rb0 + 32 + r) * 128 + (col ^ (((r >> 2) & 3) << 4))] = run;
            run += bf2f(xv1[r]);
        }
    }
    __syncthreads();

    // Dot: all 4 waves. Wave covers rows wm..wm+63, cols wn..wn+63.
    {
        const int psw = quad << 4;
        float wv[4]; int cswz[4];
        #pragma unroll
        for (int nt = 0; nt < 4; ++nt) {
            wv[nt]   = w[n0 + wn + nt * 16 + l16];
            cswz[nt] = (wn + nt * 16 + l16) ^ psw;
        }
        #pragma unroll
        for (int mt = 0; mt < 4; ++mt) {
            #pragma unroll
            for (int r = 0; r < 4; ++r) {
                const int m_loc = wm + mt * 16 + quad * 4 + r;
                float val = 0.f;
                #pragma unroll
                for (int nt = 0; nt < 4; ++nt)
                    val += (acc[mt][nt][r] + wv[nt]) * sP[m_loc * 128 + cswz[nt]];
                val += __shfl_xor(val, 1, 64);
                val += __shfl_xor(val, 2, 64);
                val += __shfl_xor(val, 4, 64);
                val += __shfl_xor(val, 8, 64);
                if (l16 == 0)
                    s1part[(size_t)(m0 + m_loc) * 16 + by * 2 + (wave & 1)] = val;
            }
        }
    }
}

// ---------------------------------------------------------------- K4: bcast (per chunk)
// out[r][:] = sum16(s1part[r]) + r*(sum8(s2part[r]) + c)
__global__ __launch_bounds__(256) void bcast(
    const float* __restrict__ s1part, const float* __restrict__ s2part,
    const float* __restrict__ cval, float* __restrict__ out)
{
    __shared__ float rowval[CHROW];
    const int t = threadIdx.x, ch = blockIdx.x;
    if (t < CHROW) {
        const size_t row = (size_t)ch * CHROW + t;
        const float* p = &s1part[row * 16];
        float s = 0.f;
        #pragma unroll
        for (int j = 0; j < 16; ++j) s += p[j];
        const float* p2 = &s2part[row * 8];
        float s2 = 0.f;
        #pragma unroll
        for (int j = 0; j < 8; ++j) s2 += p2[j];
        rowval[t] = s + (float)row * (s2 + cval[0]);
    }
    __syncthreads();
    const int c4 = t * 4;
    #pragma unroll
    for (int r = 0; r < CHROW; ++r) {
        const size_t row = (size_t)ch * CHROW + r;
        f32x4 o = (f32x4)rowval[r];
        *(f32x4*)&out[row * DIM + c4] = o;
    }
}

// ---------------------------------------------------------------- launch
extern "C" void kernel_launch(void* const* d_in, const int* in_sizes, int n_in,
                              void* d_out, int out_size, void* d_ws, size_t ws_size,
                              hipStream_t stream)
{
    const float* x  = (const float*)d_in[0];
    const float* Wk = (const float*)d_in[1];
    const float* bk = (const float*)d_in[2];
    // d_in[3] = Wv, d_in[4] = bv : dead (reference overwrites V with ones)
    const float* Wq = (const float*)d_in[5];
    const float* bq = (const float*)d_in[6];
    float* out = (float*)d_out;

    char* ws = (char*)d_ws;
    unsigned short* xb  = (unsigned short*)(ws);                          // 16 MB
    unsigned short* GTb = (unsigned short*)(ws + (size_t)(16u << 20));    //  2 MB
    unsigned short* WqT = (unsigned short*)(ws + (size_t)(18u << 20));    //  2 MB
    unsigned short* WkT = (unsigned short*)(ws + (size_t)(20u << 20));    //  2 MB
    float* sums         = (float*)(ws + (size_t)(22u << 20));             //  1 MB
    float* offs         = (float*)(ws + (size_t)(23u << 20));             //  1 MB
    float* pbuf         = (float*)(ws + (size_t)(24u << 20));             // 128 KB
    float* u            = (float*)(ws + (size_t)(24u << 20) + (140u << 10)); // 4 KB
    float* w            = (float*)(ws + (size_t)(24u << 20) + (144u << 10)); // 4 KB
    float* cval         = (float*)(ws + (size_t)(24u << 20) + (148u << 10)); // 4 B
    float* s1part       = (float*)(ws + (size_t)(25u << 20));             // 512 KB
    float* s2part       = (float*)(ws + (size_t)(25u << 20) + (512u << 10)); // 256 KB

    front<<<768, 256, 0, stream>>>(x, Wq, Wk, bk, bq, xb, WqT, WkT, pbuf, sums);
    mid<<<269, 256, 0, stream>>>(WkT, WqT, GTb, sums, offs, bq, bk, cval, pbuf, u, w);
    gemm_z_fused<<<dim3(64, 8), 256, 0, stream>>>(xb, GTb, offs, u, w, s1part, s2part);
    bcast<<<256, 256, 0, stream>>>(s1part, s2part, cval, out);
}